// Round 6
// baseline (111.832 us; speedup 1.0000x reference)
//
#include <hip/hip_runtime.h>

// SpectralDivergence: fft2(512x512) power spectrum -> radial profile (50 bins)
// -> per-batch KL divergence between softmaxed profiles of x and reference.
// 96 images (48 x + 48 ref), B=16, C=3, H=W=512. Output: 16 floats.
//
// R5: dual-FFT ILP. One wave executes TWO 512-pt FFTs lock-step interleaved
// (independent streams: B's LDS latency hides under A's fft8 and vice versa),
// shared twiddles. Cols: wave = 2 columns. Rows: wave = 2 row pairs. Keeps
// R4's PHYS swizzle (0 conflicts), staged 64B transposed writes, bf16
// intermediate (single workspace chunk).

#define NIMG 96
#define NB 50
#define NCOL 257
#define PHYS(k) ((k) ^ (((k) >> 3) & 7))

typedef unsigned int uint32;

__device__ __forceinline__ float2 cadd(float2 a, float2 b){ return make_float2(a.x+b.x, a.y+b.y); }
__device__ __forceinline__ float2 csub(float2 a, float2 b){ return make_float2(a.x-b.x, a.y-b.y); }
__device__ __forceinline__ float2 cmul(float2 a, float2 b){
  return make_float2(fmaf(a.x, b.x, -(a.y*b.y)), fmaf(a.x, b.y, a.y*b.x));
}
__device__ __forceinline__ float2 mul_mi(float2 a){ return make_float2(a.y, -a.x); }  // * -i

// pack complex -> bf16x2 (re high, im low), RNE
__device__ __forceinline__ uint32 bfpack(float re, float im) {
  uint32 ur = __float_as_uint(re); ur += 0x7FFFu + ((ur >> 16) & 1u);
  uint32 ui = __float_as_uint(im); ui += 0x7FFFu + ((ui >> 16) & 1u);
  return (ur & 0xFFFF0000u) | (ui >> 16);
}
__device__ __forceinline__ float2 bfunpack(uint32 u) {
  return make_float2(__uint_as_float(u & 0xFFFF0000u), __uint_as_float(u << 16));
}

// 8-point DFT, natural order: g[r] <- sum_a g[a] * W8^{a r}
__device__ __forceinline__ void fft8(float2 g[8]) {
  const float C = 0.70710678118654752f;
  float2 e0=g[0], e1=g[2], e2=g[4], e3=g[6];
  float2 o0=g[1], o1=g[3], o2=g[5], o3=g[7];
  float2 t0=cadd(e0,e2), t1=csub(e0,e2), t2=cadd(e1,e3), t3m=mul_mi(csub(e1,e3));
  float2 E0=cadd(t0,t2), E1=cadd(t1,t3m), E2=csub(t0,t2), E3=csub(t1,t3m);
  float2 s0=cadd(o0,o2), s1=csub(o0,o2), s2=cadd(o1,o3), s3m=mul_mi(csub(o1,o3));
  float2 O0=cadd(s0,s2), O1=cadd(s1,s3m), O2=csub(s0,s2), O3=csub(s1,s3m);
  O1 = make_float2(C*(O1.x+O1.y), C*(O1.y-O1.x));      // * W8^1
  O2 = mul_mi(O2);                                      // * W8^2
  O3 = make_float2(C*(O3.y-O3.x), -C*(O3.x+O3.y));      // * W8^3
  g[0]=cadd(E0,O0); g[4]=csub(E0,O0);
  g[1]=cadd(E1,O1); g[5]=csub(E1,O1);
  g[2]=cadd(E2,O2); g[6]=csub(E2,O2);
  g[3]=cadd(E3,O3); g[7]=csub(E3,O3);
}

// Dual wave-local 512-pt FFT (two independent FFTs, phase-interleaved).
// Input: x[a] = data[64a + lane]; output x[q] = X[(lane>>3)+8*(lane&7)+64q].
__device__ __forceinline__ void wave_fft512_dual(
    float2 xA[8], float2 xB[8],
    float2* __restrict__ zA, float2* __restrict__ zB,
    const float2 tw1[7], const float2 tw2[7], int lane)
{
  const int hi = lane >> 3, lo = lane & 7;
  fft8(xA); fft8(xB);
  #pragma unroll
  for (int r = 1; r < 8; ++r) { xA[r] = cmul(xA[r], tw1[r-1]); xB[r] = cmul(xB[r], tw1[r-1]); }
  #pragma unroll
  for (int r = 0; r < 8; ++r) {
    int idx = 64*r + 8*(hi ^ r) + lo;
    zA[idx] = xA[r]; zB[idx] = xB[r];
  }
  __builtin_amdgcn_wave_barrier();
  #pragma unroll
  for (int ap = 0; ap < 8; ++ap) {
    int idx = 64*hi + 8*(ap ^ hi) + lo;
    xA[ap] = zA[idx]; xB[ap] = zB[idx];
  }
  __builtin_amdgcn_wave_barrier();
  fft8(xA); fft8(xB);
  #pragma unroll
  for (int rp = 1; rp < 8; ++rp) { xA[rp] = cmul(xA[rp], tw2[rp-1]); xB[rp] = cmul(xB[rp], tw2[rp-1]); }
  #pragma unroll
  for (int rp = 0; rp < 8; ++rp) {
    int idx = 64*hi + 8*(rp ^ hi) + (lo ^ rp);
    zA[idx] = xA[rp]; zB[idx] = xB[rp];
  }
  __builtin_amdgcn_wave_barrier();
  #pragma unroll
  for (int bp = 0; bp < 8; ++bp) {
    int idx = 64*hi + 8*(lo ^ hi) + (bp ^ lo);
    xA[bp] = zA[idx]; xB[bp] = zB[idx];
  }
  __builtin_amdgcn_wave_barrier();
  fft8(xA); fft8(xB);                       // x[q] = X[hi + 8*lo + 64q]
}

#define TWIDDLE_INIT(tw1, tw2, lane)                                        \
  {                                                                         \
    float sv, cv;                                                           \
    __sincosf(-6.283185307179586f * (float)(lane) / 512.f, &sv, &cv);       \
    float2 w1 = make_float2(cv, sv);                                        \
    tw1[0] = w1;                                                            \
    _Pragma("unroll")                                                       \
    for (int r = 1; r < 7; ++r) tw1[r] = cmul(tw1[r-1], w1);                \
    __sincosf(-6.283185307179586f * (float)((lane) & 7) / 64.f, &sv, &cv);  \
    float2 w2 = make_float2(cv, sv);                                        \
    tw2[0] = w2;                                                            \
    _Pragma("unroll")                                                       \
    for (int r = 1; r < 7; ++r) tw2[r] = cmul(tw2[r-1], w2);                \
  }

// ---------------------------------------------------------------------------
// Row pass: 2-for-1 packed real row FFTs, TWO row pairs per wave.
// Block = 4 waves = 8 row pairs = 16 rows; 32 blocks/image.
// Output transposed bf16-packed, staged in LDS, written as 64B chunks.
// ---------------------------------------------------------------------------
__global__ __launch_bounds__(256, 4) void fft_rows_T(
    const float* __restrict__ xin, const float* __restrict__ rin,
    uint32* __restrict__ outT, int img0)
{
  __shared__ float2 s_z[8][512];        // 32 KB (2 buffers per wave)
  __shared__ uint2  s_stage[64][8];     // 4 KB
  const int tid = threadIdx.x, w = tid >> 6, lane = tid & 63;
  const int imgL = blockIdx.x >> 5, blkin = blockIdx.x & 31;
  const int img = img0 + imgL;
  const float* base = (img < 48) ? (xin + (size_t)img * 262144)
                                 : (rin + (size_t)(img - 48) * 262144);
  const int rpA = blkin * 8 + w;        // rows 2rpA, 2rpA+1
  const int rpB = rpA + 4;
  const float* srcA = base + (size_t)rpA * 1024;
  const float* srcB = base + (size_t)rpB * 1024;

  float2 tw1[7], tw2[7];
  TWIDDLE_INIT(tw1, tw2, lane)
  float2* zA = s_z[2*w];
  float2* zB = s_z[2*w + 1];
  uint32* outImg = outT + (size_t)imgL * ((size_t)NCOL * 512);

  float2 xA[8], xB[8];
  #pragma unroll
  for (int a = 0; a < 8; ++a) {
    xA[a] = make_float2(srcA[64*a + lane], srcA[512 + 64*a + lane]);
    xB[a] = make_float2(srcB[64*a + lane], srcB[512 + 64*a + lane]);
  }
  wave_fft512_dual(xA, xB, zA, zB, tw1, tw2, lane);

  // natural-order store, PHYS-swizzled (conflict-free)
  const int hi = lane >> 3, lo = lane & 7;
  #pragma unroll
  for (int q = 0; q < 8; ++q) {
    int idx = PHYS(hi + 8*lo + 64*q);
    zA[idx] = xA[q]; zB[idx] = xB[q];
  }
  __builtin_amdgcn_wave_barrier();

  // conjugate-symmetry separation + staged 64B-coalesced transposed write
  #pragma unroll
  for (int a = 0; a < 4; ++a) {
    const int k  = 64 * a + lane;                 // 0..255
    const int pk = (512 - k) & 511;
    float2 zkA = zA[PHYS(k)], zpA = zA[PHYS(pk)];
    float2 zkB = zB[PHYS(k)], zpB = zB[PHYS(pk)];
    uint32 uA0 = bfpack(0.5f*(zkA.x + zpA.x), 0.5f*(zkA.y - zpA.y));  // row 2rpA
    uint32 uA1 = bfpack(0.5f*(zkA.y + zpA.y), 0.5f*(zpA.x - zkA.x));  // row 2rpA+1
    uint32 uB0 = bfpack(0.5f*(zkB.x + zpB.x), 0.5f*(zkB.y - zpB.y));  // row 2rpB
    uint32 uB1 = bfpack(0.5f*(zkB.y + zpB.y), 0.5f*(zpB.x - zkB.x));  // row 2rpB+1
    s_stage[lane][(w + lane) & 7]     = make_uint2(uA0, uA1);
    s_stage[lane][(w + 4 + lane) & 7] = make_uint2(uB0, uB1);
    __syncthreads();
    const int kk = tid >> 2, jj = (tid & 3) * 2;   // kk: 0..63, jj: 0,2,4,6
    uint2 v0 = s_stage[kk][(jj + kk) & 7];
    uint2 v1 = s_stage[kk][(jj + 1 + kk) & 7];
    *reinterpret_cast<uint4*>(outImg + ((size_t)(64*a + kk) * 512
                                        + 16*blkin + 2*jj)) =
        make_uint4(v0.x, v0.y, v1.x, v1.y);
    __syncthreads();
  }
  if (lane == 0) {   // col 256 (self-paired): A=Re(Z), B=Im(Z)
    float2 znA = zA[256], znB = zB[256];   // PHYS(256)==256
    *reinterpret_cast<uint2*>(outImg + ((size_t)256 * 512 + 2 * rpA)) =
        make_uint2(bfpack(znA.x, 0.f), bfpack(znA.y, 0.f));
    *reinterpret_cast<uint2*>(outImg + ((size_t)256 * 512 + 2 * rpB)) =
        make_uint2(bfpack(znB.x, 0.f), bfpack(znB.y, 0.f));
  }
}

// ---------------------------------------------------------------------------
// Col pass: TWO column FFTs per wave + fused power/radial-bin (Hermitian
// weight). Block = 4 waves = 8 columns; 33 blocks/image (cols 0..256).
// Tail handled branchlessly: clamp column, weight 0.
// ---------------------------------------------------------------------------
__global__ __launch_bounds__(256, 4) void fft_cols_bin(
    const uint32* __restrict__ inT, float* __restrict__ profSum, int img0)
{
  __shared__ float2 s_z[8][512];        // 32 KB
  __shared__ float s_bins[4][64];       // 1 KB
  const int tid = threadIdx.x, w = tid >> 6, lane = tid & 63;
  const int imgL = blockIdx.x / 33, blkin = blockIdx.x - imgL * 33;
  const int imgG = img0 + imgL;
  const int cA = blkin * 8 + w;
  const int cB = cA + 4;
  const int csA = (cA <= 256) ? cA : 256;
  const int csB = (cB <= 256) ? cB : 256;
  const float wfA = (cA > 256) ? 0.f : ((cA == 0 || cA == 256) ? 1.f : 2.f);
  const float wfB = (cB > 256) ? 0.f : ((cB == 0 || cB == 256) ? 1.f : 2.f);
  s_bins[w][lane] = 0.f;   // wave-private

  float2 tw1[7], tw2[7];
  TWIDDLE_INIT(tw1, tw2, lane)
  const uint32* srcA = inT + ((size_t)(imgL * NCOL + csA)) * 512;
  const uint32* srcB = inT + ((size_t)(imgL * NCOL + csB)) * 512;
  float2 xA[8], xB[8];
  #pragma unroll
  for (int a = 0; a < 8; ++a) {
    xA[a] = bfunpack(srcA[64*a + lane]);
    xB[a] = bfunpack(srcB[64*a + lane]);
  }
  wave_fft512_dual(xA, xB, s_z[2*w], s_z[2*w+1], tw1, tw2, lane);

  const float sxA2 = (float)(csA * csA);
  const float sxB2 = (float)(csB * csB);
  const int low6 = (lane >> 3) + 8 * (lane & 7);
  #pragma unroll
  for (int q = 0; q < 8; ++q) {
    int kout = low6 + 64 * q;
    int sy = (q >= 4) ? (kout - 512) : kout;
    float sy2 = (float)(sy * sy);
    float pA = wfA * (xA[q].x * xA[q].x + xA[q].y * xA[q].y);
    float pB = wfB * (xB[q].x * xB[q].x + xB[q].y * xB[q].y);
    int bbA = (int)(sqrtf(sy2 + sxA2) * 0.1953125f);   // 50/256 exact
    int bbB = (int)(sqrtf(sy2 + sxB2) * 0.1953125f);
    if (bbA < NB) atomicAdd(&s_bins[w][bbA], pA);
    if (bbB < NB) atomicAdd(&s_bins[w][bbB], pB);
  }
  __syncthreads();
  if (tid < NB) {
    float s = s_bins[0][tid] + s_bins[1][tid] + s_bins[2][tid] + s_bins[3][tid];
    atomicAdd(&profSum[(size_t)imgG * NB + tid], s);
  }
}

// ---------------------------------------------------------------------------
// Radial bin counts (geometry only). 128 blocks x 2048 pixels.
// ---------------------------------------------------------------------------
__global__ __launch_bounds__(256) void compute_counts(float* __restrict__ cnt)
{
  const int t = threadIdx.x;
  __shared__ float lb[NB];
  if (t < NB) lb[t] = 0.f;
  __syncthreads();
  const int base = blockIdx.x * 2048;
  #pragma unroll
  for (int k = 0; k < 8; ++k) {
    const int idx = base + k * 256 + t;
    const int y  = idx >> 9;
    const int xx = idx & 511;
    const int sy = (y < 256) ? y : y - 512;
    const int sx = (xx < 256) ? xx : xx - 512;
    float r = sqrtf((float)(sy * sy + sx * sx));
    int bb = (int)(r * 0.1953125f);
    if (bb < NB) atomicAdd(&lb[bb], 1.f);
  }
  __syncthreads();
  if (t < NB) atomicAdd(&cnt[t], lb[t]);
}

// ---------------------------------------------------------------------------
// Finalize: profile means -> log_softmax -> KL. One block per batch.
// ---------------------------------------------------------------------------
__global__ __launch_bounds__(256) void finalize_kl(
    const float* __restrict__ profSum, const float* __restrict__ cntg,
    float* __restrict__ out)
{
  const int b = blockIdx.x;
  const int t = threadIdx.x;
  __shared__ float red[256];

  float lxv = -3.0e38f, lrv = -3.0e38f;
  if (t < 150) {
    const int cc  = t / NB;
    const int bin = t - cc * NB;
    const float c = cntg[bin];
    lxv = profSum[(size_t)(b * 3 + cc) * NB + bin] / c;
    lrv = profSum[(size_t)(48 + b * 3 + cc) * NB + bin] / c;
  }
  auto rmax = [&](float v) {
    red[t] = v; __syncthreads();
    for (int s2 = 128; s2 >= 1; s2 >>= 1) {
      if (t < s2) red[t] = fmaxf(red[t], red[t + s2]);
      __syncthreads();
    }
    float rr = red[0]; __syncthreads();
    return rr;
  };
  auto rsum = [&](float v) {
    red[t] = v; __syncthreads();
    for (int s2 = 128; s2 >= 1; s2 >>= 1) {
      if (t < s2) red[t] = red[t] + red[t + s2];
      __syncthreads();
    }
    float rr = red[0]; __syncthreads();
    return rr;
  };
  const float mx  = rmax(lxv);
  const float mr  = rmax(lrv);
  const float sx  = rsum((t < 150) ? expf(lxv - mx) : 0.f);
  const float sr  = rsum((t < 150) ? expf(lrv - mr) : 0.f);
  const float lsx = logf(sx);
  const float lsr = logf(sr);
  float term = 0.f;
  if (t < 150) {
    const float logp = lxv - mx - lsx;
    const float logq = lrv - mr - lsr;
    const float q    = expf(logq);
    term = q * (logq - logp);
  }
  const float div = rsum(term);
  if (t == 0) out[b] = div;
}

// ---------------------------------------------------------------------------
extern "C" void kernel_launch(void* const* d_in, const int* in_sizes, int n_in,
                              void* d_out, int out_size, void* d_ws, size_t ws_size,
                              hipStream_t stream)
{
  const float* x = (const float*)d_in[0];
  const float* r = (const float*)d_in[1];
  float* out     = (float*)d_out;

  // ws layout: [0,19200) profile sums (96x50); [19200,19400) bin counts;
  // [19456, ...) chunked bf16-packed transposed spectrum (257 cols/img).
  float* profSum = (float*)d_ws;
  float* cnt     = (float*)((char*)d_ws + 19200);
  const size_t IM_OFS = 19456;
  uint32* interT = (uint32*)((char*)d_ws + IM_OFS);

  const size_t perImg = (size_t)NCOL * 512 * sizeof(uint32);  // ~514 KiB
  size_t avail = (ws_size > IM_OFS) ? (ws_size - IM_OFS) : 0;
  int ic = (int)(avail / perImg);
  if (ic > NIMG) ic = NIMG;
  if (ic < 1) ic = 1;

  hipMemsetAsync(d_ws, 0, IM_OFS, stream);
  hipLaunchKernelGGL(compute_counts, dim3(128), dim3(256), 0, stream, cnt);

  for (int img0 = 0; img0 < NIMG; img0 += ic) {
    const int n = (NIMG - img0 < ic) ? (NIMG - img0) : ic;
    hipLaunchKernelGGL(fft_rows_T, dim3(n * 32), dim3(256), 0, stream,
                       x, r, interT, img0);
    hipLaunchKernelGGL(fft_cols_bin, dim3(n * 33), dim3(256), 0, stream,
                       interT, profSum, img0);
  }
  hipLaunchKernelGGL(finalize_kl, dim3(16), dim3(256), 0, stream,
                     profSum, cnt, out);
}

// Round 7
// 111.817 us; speedup vs baseline: 1.0001x; 1.0001x over previous
//
#include <hip/hip_runtime.h>

// SpectralDivergence: fft2(512x512) power spectrum -> radial profile (50 bins)
// -> per-batch KL divergence between softmaxed profiles of x and reference.
// 96 images (48 x + 48 ref), B=16, C=3, H=W=512. Output: 16 floats.
//
// R6: SCRATCH ELIMINATION. Previous rounds passed float2 arrays (x[8],
// tw1[7], tw2[7]) across function boundaries; reported VGPR counts (24/52)
// were below the live-value minimum => arrays were demoted to per-lane
// scratch, making every fft8 a string of scattered HBM/L2 round-trips
// (per-FFT chain ~50K cycles vs ~2.6K modeled). This version has ZERO
// memory-shaped locals: fft8 is a by-value struct fn with named members,
// the dual FFT is a flat macro, twiddles are a 2-register recurrence.

#define NIMG 96
#define NB 50
#define NCOL 257
#define PHYS(k) ((k) ^ (((k) >> 3) & 7))

typedef unsigned int uint32;

__device__ __forceinline__ float2 cadd(float2 a, float2 b){ return make_float2(a.x+b.x, a.y+b.y); }
__device__ __forceinline__ float2 csub(float2 a, float2 b){ return make_float2(a.x-b.x, a.y-b.y); }
__device__ __forceinline__ float2 cmul(float2 a, float2 b){
  return make_float2(fmaf(a.x, b.x, -(a.y*b.y)), fmaf(a.x, b.y, a.y*b.x));
}
__device__ __forceinline__ float2 mul_mi(float2 a){ return make_float2(a.y, -a.x); }  // * -i

// pack complex -> bf16x2 (re high, im low), RNE
__device__ __forceinline__ uint32 bfpack(float re, float im) {
  uint32 ur = __float_as_uint(re); ur += 0x7FFFu + ((ur >> 16) & 1u);
  uint32 ui = __float_as_uint(im); ui += 0x7FFFu + ((ui >> 16) & 1u);
  return (ur & 0xFFFF0000u) | (ui >> 16);
}
__device__ __forceinline__ float2 bfunpack(uint32 u) {
  return make_float2(__uint_as_float(u & 0xFFFF0000u), __uint_as_float(u << 16));
}

// 8 complex values in named registers — never indexed, never addressed.
struct C8 { float2 m0, m1, m2, m3, m4, m5, m6, m7; };

// 8-point DFT, natural order (by value in, by value out).
__device__ __forceinline__ C8 fft8(C8 v) {
  const float C = 0.70710678118654752f;
  float2 t0=cadd(v.m0,v.m4), t1=csub(v.m0,v.m4);
  float2 t2=cadd(v.m2,v.m6), t3m=mul_mi(csub(v.m2,v.m6));
  float2 E0=cadd(t0,t2), E1=cadd(t1,t3m), E2=csub(t0,t2), E3=csub(t1,t3m);
  float2 s0=cadd(v.m1,v.m5), s1=csub(v.m1,v.m5);
  float2 s2=cadd(v.m3,v.m7), s3m=mul_mi(csub(v.m3,v.m7));
  float2 O0=cadd(s0,s2), O1=cadd(s1,s3m), O2=csub(s0,s2), O3=csub(s1,s3m);
  O1 = make_float2(C*(O1.x+O1.y), C*(O1.y-O1.x));      // * W8^1
  O2 = mul_mi(O2);                                      // * W8^2
  O3 = make_float2(C*(O3.y-O3.x), -C*(O3.x+O3.y));      // * W8^3
  C8 r;
  r.m0=cadd(E0,O0); r.m4=csub(E0,O0);
  r.m1=cadd(E1,O1); r.m5=csub(E1,O1);
  r.m2=cadd(E2,O2); r.m6=csub(E2,O2);
  r.m3=cadd(E3,O3); r.m7=csub(E3,O3);
  return r;
}

// twiddle recurrence applied to members 1..7 of XA and XB (shared t chain)
#define TWAPPLY(XA, XB, W) do { float2 t_ = (W);                        \
  XA.m1=cmul(XA.m1,t_); XB.m1=cmul(XB.m1,t_); t_=cmul(t_,(W));          \
  XA.m2=cmul(XA.m2,t_); XB.m2=cmul(XB.m2,t_); t_=cmul(t_,(W));          \
  XA.m3=cmul(XA.m3,t_); XB.m3=cmul(XB.m3,t_); t_=cmul(t_,(W));          \
  XA.m4=cmul(XA.m4,t_); XB.m4=cmul(XB.m4,t_); t_=cmul(t_,(W));          \
  XA.m5=cmul(XA.m5,t_); XB.m5=cmul(XB.m5,t_); t_=cmul(t_,(W));          \
  XA.m6=cmul(XA.m6,t_); XB.m6=cmul(XB.m6,t_); t_=cmul(t_,(W));          \
  XA.m7=cmul(XA.m7,t_); XB.m7=cmul(XB.m7,t_); } while(0)

// Dual wave-local 512-pt FFT. Input: x.mA = data[64a + lane]; output:
// x.mq = X[(lane>>3) + 8*(lane&7) + 64q]. XOR-swizzled LDS exchanges
// (conflict-free at b64 granularity), wave-synchronous (no __syncthreads).
#define DUAL_FFT512(XA, XB, ZA, ZB, W1, W2, HI, LO) do {                      \
  XA = fft8(XA); XB = fft8(XB);                                               \
  TWAPPLY(XA, XB, W1);                                                        \
  ZA[      8*((HI)^0)+(LO)] = XA.m0;  ZB[      8*((HI)^0)+(LO)] = XB.m0;      \
  ZA[ 64 + 8*((HI)^1)+(LO)] = XA.m1;  ZB[ 64 + 8*((HI)^1)+(LO)] = XB.m1;      \
  ZA[128 + 8*((HI)^2)+(LO)] = XA.m2;  ZB[128 + 8*((HI)^2)+(LO)] = XB.m2;      \
  ZA[192 + 8*((HI)^3)+(LO)] = XA.m3;  ZB[192 + 8*((HI)^3)+(LO)] = XB.m3;      \
  ZA[256 + 8*((HI)^4)+(LO)] = XA.m4;  ZB[256 + 8*((HI)^4)+(LO)] = XB.m4;      \
  ZA[320 + 8*((HI)^5)+(LO)] = XA.m5;  ZB[320 + 8*((HI)^5)+(LO)] = XB.m5;      \
  ZA[384 + 8*((HI)^6)+(LO)] = XA.m6;  ZB[384 + 8*((HI)^6)+(LO)] = XB.m6;      \
  ZA[448 + 8*((HI)^7)+(LO)] = XA.m7;  ZB[448 + 8*((HI)^7)+(LO)] = XB.m7;      \
  __builtin_amdgcn_wave_barrier();                                            \
  XA.m0 = ZA[64*(HI)+8*(0^(HI))+(LO)]; XB.m0 = ZB[64*(HI)+8*(0^(HI))+(LO)];   \
  XA.m1 = ZA[64*(HI)+8*(1^(HI))+(LO)]; XB.m1 = ZB[64*(HI)+8*(1^(HI))+(LO)];   \
  XA.m2 = ZA[64*(HI)+8*(2^(HI))+(LO)]; XB.m2 = ZB[64*(HI)+8*(2^(HI))+(LO)];   \
  XA.m3 = ZA[64*(HI)+8*(3^(HI))+(LO)]; XB.m3 = ZB[64*(HI)+8*(3^(HI))+(LO)];   \
  XA.m4 = ZA[64*(HI)+8*(4^(HI))+(LO)]; XB.m4 = ZB[64*(HI)+8*(4^(HI))+(LO)];   \
  XA.m5 = ZA[64*(HI)+8*(5^(HI))+(LO)]; XB.m5 = ZB[64*(HI)+8*(5^(HI))+(LO)];   \
  XA.m6 = ZA[64*(HI)+8*(6^(HI))+(LO)]; XB.m6 = ZB[64*(HI)+8*(6^(HI))+(LO)];   \
  XA.m7 = ZA[64*(HI)+8*(7^(HI))+(LO)]; XB.m7 = ZB[64*(HI)+8*(7^(HI))+(LO)];   \
  __builtin_amdgcn_wave_barrier();                                            \
  XA = fft8(XA); XB = fft8(XB);                                               \
  TWAPPLY(XA, XB, W2);                                                        \
  ZA[64*(HI)+8*(0^(HI))+((LO)^0)] = XA.m0; ZB[64*(HI)+8*(0^(HI))+((LO)^0)] = XB.m0; \
  ZA[64*(HI)+8*(1^(HI))+((LO)^1)] = XA.m1; ZB[64*(HI)+8*(1^(HI))+((LO)^1)] = XB.m1; \
  ZA[64*(HI)+8*(2^(HI))+((LO)^2)] = XA.m2; ZB[64*(HI)+8*(2^(HI))+((LO)^2)] = XB.m2; \
  ZA[64*(HI)+8*(3^(HI))+((LO)^3)] = XA.m3; ZB[64*(HI)+8*(3^(HI))+((LO)^3)] = XB.m3; \
  ZA[64*(HI)+8*(4^(HI))+((LO)^4)] = XA.m4; ZB[64*(HI)+8*(4^(HI))+((LO)^4)] = XB.m4; \
  ZA[64*(HI)+8*(5^(HI))+((LO)^5)] = XA.m5; ZB[64*(HI)+8*(5^(HI))+((LO)^5)] = XB.m5; \
  ZA[64*(HI)+8*(6^(HI))+((LO)^6)] = XA.m6; ZB[64*(HI)+8*(6^(HI))+((LO)^6)] = XB.m6; \
  ZA[64*(HI)+8*(7^(HI))+((LO)^7)] = XA.m7; ZB[64*(HI)+8*(7^(HI))+((LO)^7)] = XB.m7; \
  __builtin_amdgcn_wave_barrier();                                            \
  XA.m0 = ZA[64*(HI)+8*((LO)^(HI))+(0^(LO))]; XB.m0 = ZB[64*(HI)+8*((LO)^(HI))+(0^(LO))]; \
  XA.m1 = ZA[64*(HI)+8*((LO)^(HI))+(1^(LO))]; XB.m1 = ZB[64*(HI)+8*((LO)^(HI))+(1^(LO))]; \
  XA.m2 = ZA[64*(HI)+8*((LO)^(HI))+(2^(LO))]; XB.m2 = ZB[64*(HI)+8*((LO)^(HI))+(2^(LO))]; \
  XA.m3 = ZA[64*(HI)+8*((LO)^(HI))+(3^(LO))]; XB.m3 = ZB[64*(HI)+8*((LO)^(HI))+(3^(LO))]; \
  XA.m4 = ZA[64*(HI)+8*((LO)^(HI))+(4^(LO))]; XB.m4 = ZB[64*(HI)+8*((LO)^(HI))+(4^(LO))]; \
  XA.m5 = ZA[64*(HI)+8*((LO)^(HI))+(5^(LO))]; XB.m5 = ZB[64*(HI)+8*((LO)^(HI))+(5^(LO))]; \
  XA.m6 = ZA[64*(HI)+8*((LO)^(HI))+(6^(LO))]; XB.m6 = ZB[64*(HI)+8*((LO)^(HI))+(6^(LO))]; \
  XA.m7 = ZA[64*(HI)+8*((LO)^(HI))+(7^(LO))]; XB.m7 = ZB[64*(HI)+8*((LO)^(HI))+(7^(LO))]; \
  __builtin_amdgcn_wave_barrier();                                            \
  XA = fft8(XA); XB = fft8(XB);                                               \
} while(0)

#define TWIDDLE_W(W1, W2, lane)                                             \
  float2 W1, W2;                                                            \
  {                                                                         \
    float sv, cv;                                                           \
    __sincosf(-6.283185307179586f * (float)(lane) / 512.f, &sv, &cv);       \
    W1 = make_float2(cv, sv);                                               \
    __sincosf(-6.283185307179586f * (float)((lane) & 7) / 64.f, &sv, &cv);  \
    W2 = make_float2(cv, sv);                                               \
  }

// ---------------------------------------------------------------------------
// Row pass: 2-for-1 packed real row FFTs, TWO row pairs per wave.
// Block = 4 waves = 8 row pairs = 16 rows; 32 blocks/image.
// Output transposed bf16-packed, staged in LDS, written as 64B chunks.
// ---------------------------------------------------------------------------
__global__ __launch_bounds__(256, 4) void fft_rows_T(
    const float* __restrict__ xin, const float* __restrict__ rin,
    uint32* __restrict__ outT, int img0)
{
  __shared__ float2 s_z[8][512];        // 32 KB (2 buffers per wave)
  __shared__ uint2  s_stage[64][8];     // 4 KB
  const int tid = threadIdx.x, w = tid >> 6, lane = tid & 63;
  const int hi = lane >> 3, lo = lane & 7;
  const int imgL = blockIdx.x >> 5, blkin = blockIdx.x & 31;
  const int img = img0 + imgL;
  const float* base = (img < 48) ? (xin + (size_t)img * 262144)
                                 : (rin + (size_t)(img - 48) * 262144);
  const int rpA = blkin * 8 + w;        // rows 2rpA, 2rpA+1
  const int rpB = rpA + 4;
  const float* srcA = base + (size_t)rpA * 1024;
  const float* srcB = base + (size_t)rpB * 1024;

  TWIDDLE_W(w1, w2, lane)
  float2* zA = s_z[2*w];
  float2* zB = s_z[2*w + 1];
  uint32* outImg = outT + (size_t)imgL * ((size_t)NCOL * 512);

  C8 xA, xB;
  xA.m0 = make_float2(srcA[      lane], srcA[512 +       lane]);
  xA.m1 = make_float2(srcA[ 64 + lane], srcA[512 +  64 + lane]);
  xA.m2 = make_float2(srcA[128 + lane], srcA[512 + 128 + lane]);
  xA.m3 = make_float2(srcA[192 + lane], srcA[512 + 192 + lane]);
  xA.m4 = make_float2(srcA[256 + lane], srcA[512 + 256 + lane]);
  xA.m5 = make_float2(srcA[320 + lane], srcA[512 + 320 + lane]);
  xA.m6 = make_float2(srcA[384 + lane], srcA[512 + 384 + lane]);
  xA.m7 = make_float2(srcA[448 + lane], srcA[512 + 448 + lane]);
  xB.m0 = make_float2(srcB[      lane], srcB[512 +       lane]);
  xB.m1 = make_float2(srcB[ 64 + lane], srcB[512 +  64 + lane]);
  xB.m2 = make_float2(srcB[128 + lane], srcB[512 + 128 + lane]);
  xB.m3 = make_float2(srcB[192 + lane], srcB[512 + 192 + lane]);
  xB.m4 = make_float2(srcB[256 + lane], srcB[512 + 256 + lane]);
  xB.m5 = make_float2(srcB[320 + lane], srcB[512 + 320 + lane]);
  xB.m6 = make_float2(srcB[384 + lane], srcB[512 + 384 + lane]);
  xB.m7 = make_float2(srcB[448 + lane], srcB[512 + 448 + lane]);

  DUAL_FFT512(xA, xB, zA, zB, w1, w2, hi, lo);

  // natural-order store, PHYS-swizzled (conflict-free)
  zA[PHYS(hi + 8*lo +   0)] = xA.m0;  zB[PHYS(hi + 8*lo +   0)] = xB.m0;
  zA[PHYS(hi + 8*lo +  64)] = xA.m1;  zB[PHYS(hi + 8*lo +  64)] = xB.m1;
  zA[PHYS(hi + 8*lo + 128)] = xA.m2;  zB[PHYS(hi + 8*lo + 128)] = xB.m2;
  zA[PHYS(hi + 8*lo + 192)] = xA.m3;  zB[PHYS(hi + 8*lo + 192)] = xB.m3;
  zA[PHYS(hi + 8*lo + 256)] = xA.m4;  zB[PHYS(hi + 8*lo + 256)] = xB.m4;
  zA[PHYS(hi + 8*lo + 320)] = xA.m5;  zB[PHYS(hi + 8*lo + 320)] = xB.m5;
  zA[PHYS(hi + 8*lo + 384)] = xA.m6;  zB[PHYS(hi + 8*lo + 384)] = xB.m6;
  zA[PHYS(hi + 8*lo + 448)] = xA.m7;  zB[PHYS(hi + 8*lo + 448)] = xB.m7;
  __builtin_amdgcn_wave_barrier();

  // conjugate-symmetry separation + staged 64B-coalesced transposed write
  #pragma unroll
  for (int a = 0; a < 4; ++a) {
    const int k  = 64 * a + lane;                 // 0..255
    const int pk = (512 - k) & 511;
    float2 zkA = zA[PHYS(k)], zpA = zA[PHYS(pk)];
    float2 zkB = zB[PHYS(k)], zpB = zB[PHYS(pk)];
    uint32 uA0 = bfpack(0.5f*(zkA.x + zpA.x), 0.5f*(zkA.y - zpA.y));  // row 2rpA
    uint32 uA1 = bfpack(0.5f*(zkA.y + zpA.y), 0.5f*(zpA.x - zkA.x));  // row 2rpA+1
    uint32 uB0 = bfpack(0.5f*(zkB.x + zpB.x), 0.5f*(zkB.y - zpB.y));  // row 2rpB
    uint32 uB1 = bfpack(0.5f*(zkB.y + zpB.y), 0.5f*(zpB.x - zkB.x));  // row 2rpB+1
    s_stage[lane][(w + lane) & 7]     = make_uint2(uA0, uA1);
    s_stage[lane][(w + 4 + lane) & 7] = make_uint2(uB0, uB1);
    __syncthreads();
    const int kk = tid >> 2, jj = (tid & 3) * 2;   // kk: 0..63, jj: 0,2,4,6
    uint2 v0 = s_stage[kk][(jj + kk) & 7];
    uint2 v1 = s_stage[kk][(jj + 1 + kk) & 7];
    *reinterpret_cast<uint4*>(outImg + ((size_t)(64*a + kk) * 512
                                        + 16*blkin + 2*jj)) =
        make_uint4(v0.x, v0.y, v1.x, v1.y);
    __syncthreads();
  }
  if (lane == 0) {   // col 256 (self-paired): A=Re(Z), B=Im(Z)
    float2 znA = zA[256], znB = zB[256];   // PHYS(256)==256
    *reinterpret_cast<uint2*>(outImg + ((size_t)256 * 512 + 2 * rpA)) =
        make_uint2(bfpack(znA.x, 0.f), bfpack(znA.y, 0.f));
    *reinterpret_cast<uint2*>(outImg + ((size_t)256 * 512 + 2 * rpB)) =
        make_uint2(bfpack(znB.x, 0.f), bfpack(znB.y, 0.f));
  }
}

// ---------------------------------------------------------------------------
// Col pass: TWO column FFTs per wave + fused power/radial-bin (Hermitian
// weight). Block = 4 waves = 8 columns; 33 blocks/image (cols 0..256).
// ---------------------------------------------------------------------------
#define BINQ(Q, M)                                                          \
  { int kout = low6 + 64*Q;                                                 \
    int sy = (Q >= 4) ? (kout - 512) : kout;                                \
    float sy2 = (float)(sy * sy);                                           \
    float pA = wfA * (xA.M.x * xA.M.x + xA.M.y * xA.M.y);                   \
    float pB = wfB * (xB.M.x * xB.M.x + xB.M.y * xB.M.y);                   \
    int bbA = (int)(sqrtf(sy2 + sxA2) * 0.1953125f);                        \
    int bbB = (int)(sqrtf(sy2 + sxB2) * 0.1953125f);                        \
    if (bbA < NB) atomicAdd(&s_bins[w][bbA], pA);                           \
    if (bbB < NB) atomicAdd(&s_bins[w][bbB], pB); }

__global__ __launch_bounds__(256, 4) void fft_cols_bin(
    const uint32* __restrict__ inT, float* __restrict__ profSum, int img0)
{
  __shared__ float2 s_z[8][512];        // 32 KB
  __shared__ float s_bins[4][64];       // 1 KB
  const int tid = threadIdx.x, w = tid >> 6, lane = tid & 63;
  const int hi = lane >> 3, lo = lane & 7;
  const int imgL = blockIdx.x / 33, blkin = blockIdx.x - imgL * 33;
  const int imgG = img0 + imgL;
  const int cA = blkin * 8 + w;
  const int cB = cA + 4;
  const int csA = (cA <= 256) ? cA : 256;
  const int csB = (cB <= 256) ? cB : 256;
  const float wfA = (cA > 256) ? 0.f : ((cA == 0 || cA == 256) ? 1.f : 2.f);
  const float wfB = (cB > 256) ? 0.f : ((cB == 0 || cB == 256) ? 1.f : 2.f);
  s_bins[w][lane] = 0.f;   // wave-private

  TWIDDLE_W(w1, w2, lane)
  const uint32* srcA = inT + ((size_t)(imgL * NCOL + csA)) * 512;
  const uint32* srcB = inT + ((size_t)(imgL * NCOL + csB)) * 512;
  C8 xA, xB;
  xA.m0 = bfunpack(srcA[      lane]);  xB.m0 = bfunpack(srcB[      lane]);
  xA.m1 = bfunpack(srcA[ 64 + lane]);  xB.m1 = bfunpack(srcB[ 64 + lane]);
  xA.m2 = bfunpack(srcA[128 + lane]);  xB.m2 = bfunpack(srcB[128 + lane]);
  xA.m3 = bfunpack(srcA[192 + lane]);  xB.m3 = bfunpack(srcB[192 + lane]);
  xA.m4 = bfunpack(srcA[256 + lane]);  xB.m4 = bfunpack(srcB[256 + lane]);
  xA.m5 = bfunpack(srcA[320 + lane]);  xB.m5 = bfunpack(srcB[320 + lane]);
  xA.m6 = bfunpack(srcA[384 + lane]);  xB.m6 = bfunpack(srcB[384 + lane]);
  xA.m7 = bfunpack(srcA[448 + lane]);  xB.m7 = bfunpack(srcB[448 + lane]);

  DUAL_FFT512(xA, xB, (s_z[2*w]), (s_z[2*w+1]), w1, w2, hi, lo);

  const float sxA2 = (float)(csA * csA);
  const float sxB2 = (float)(csB * csB);
  const int low6 = hi + 8 * lo;
  BINQ(0, m0) BINQ(1, m1) BINQ(2, m2) BINQ(3, m3)
  BINQ(4, m4) BINQ(5, m5) BINQ(6, m6) BINQ(7, m7)
  __syncthreads();
  if (tid < NB) {
    float s = s_bins[0][tid] + s_bins[1][tid] + s_bins[2][tid] + s_bins[3][tid];
    atomicAdd(&profSum[(size_t)imgG * NB + tid], s);
  }
}

// ---------------------------------------------------------------------------
// Radial bin counts (geometry only). 128 blocks x 2048 pixels.
// ---------------------------------------------------------------------------
__global__ __launch_bounds__(256) void compute_counts(float* __restrict__ cnt)
{
  const int t = threadIdx.x;
  __shared__ float lb[NB];
  if (t < NB) lb[t] = 0.f;
  __syncthreads();
  const int base = blockIdx.x * 2048;
  #pragma unroll
  for (int k = 0; k < 8; ++k) {
    const int idx = base + k * 256 + t;
    const int y  = idx >> 9;
    const int xx = idx & 511;
    const int sy = (y < 256) ? y : y - 512;
    const int sx = (xx < 256) ? xx : xx - 512;
    float r = sqrtf((float)(sy * sy + sx * sx));
    int bb = (int)(r * 0.1953125f);
    if (bb < NB) atomicAdd(&lb[bb], 1.f);
  }
  __syncthreads();
  if (t < NB) atomicAdd(&cnt[t], lb[t]);
}

// ---------------------------------------------------------------------------
// Finalize: profile means -> log_softmax -> KL. One block per batch.
// ---------------------------------------------------------------------------
__global__ __launch_bounds__(256) void finalize_kl(
    const float* __restrict__ profSum, const float* __restrict__ cntg,
    float* __restrict__ out)
{
  const int b = blockIdx.x;
  const int t = threadIdx.x;
  __shared__ float red[256];

  float lxv = -3.0e38f, lrv = -3.0e38f;
  if (t < 150) {
    const int cc  = t / NB;
    const int bin = t - cc * NB;
    const float c = cntg[bin];
    lxv = profSum[(size_t)(b * 3 + cc) * NB + bin] / c;
    lrv = profSum[(size_t)(48 + b * 3 + cc) * NB + bin] / c;
  }
  auto rmax = [&](float v) {
    red[t] = v; __syncthreads();
    for (int s2 = 128; s2 >= 1; s2 >>= 1) {
      if (t < s2) red[t] = fmaxf(red[t], red[t + s2]);
      __syncthreads();
    }
    float rr = red[0]; __syncthreads();
    return rr;
  };
  auto rsum = [&](float v) {
    red[t] = v; __syncthreads();
    for (int s2 = 128; s2 >= 1; s2 >>= 1) {
      if (t < s2) red[t] = red[t] + red[t + s2];
      __syncthreads();
    }
    float rr = red[0]; __syncthreads();
    return rr;
  };
  const float mx  = rmax(lxv);
  const float mr  = rmax(lrv);
  const float sx  = rsum((t < 150) ? expf(lxv - mx) : 0.f);
  const float sr  = rsum((t < 150) ? expf(lrv - mr) : 0.f);
  const float lsx = logf(sx);
  const float lsr = logf(sr);
  float term = 0.f;
  if (t < 150) {
    const float logp = lxv - mx - lsx;
    const float logq = lrv - mr - lsr;
    const float q    = expf(logq);
    term = q * (logq - logp);
  }
  const float div = rsum(term);
  if (t == 0) out[b] = div;
}

// ---------------------------------------------------------------------------
extern "C" void kernel_launch(void* const* d_in, const int* in_sizes, int n_in,
                              void* d_out, int out_size, void* d_ws, size_t ws_size,
                              hipStream_t stream)
{
  const float* x = (const float*)d_in[0];
  const float* r = (const float*)d_in[1];
  float* out     = (float*)d_out;

  // ws layout: [0,19200) profile sums (96x50); [19200,19400) bin counts;
  // [19456, ...) chunked bf16-packed transposed spectrum (257 cols/img).
  float* profSum = (float*)d_ws;
  float* cnt     = (float*)((char*)d_ws + 19200);
  const size_t IM_OFS = 19456;
  uint32* interT = (uint32*)((char*)d_ws + IM_OFS);

  const size_t perImg = (size_t)NCOL * 512 * sizeof(uint32);  // ~514 KiB
  size_t avail = (ws_size > IM_OFS) ? (ws_size - IM_OFS) : 0;
  int ic = (int)(avail / perImg);
  if (ic > NIMG) ic = NIMG;
  if (ic < 1) ic = 1;

  hipMemsetAsync(d_ws, 0, IM_OFS, stream);
  hipLaunchKernelGGL(compute_counts, dim3(128), dim3(256), 0, stream, cnt);

  for (int img0 = 0; img0 < NIMG; img0 += ic) {
    const int n = (NIMG - img0 < ic) ? (NIMG - img0) : ic;
    hipLaunchKernelGGL(fft_rows_T, dim3(n * 32), dim3(256), 0, stream,
                       x, r, interT, img0);
    hipLaunchKernelGGL(fft_cols_bin, dim3(n * 33), dim3(256), 0, stream,
                       interT, profSum, img0);
  }
  hipLaunchKernelGGL(finalize_kl, dim3(16), dim3(256), 0, stream,
                     profSum, cnt, out);
}

// Round 8
// 87.871 us; speedup vs baseline: 1.2727x; 1.2725x over previous
//
#include <hip/hip_runtime.h>

// SpectralDivergence: fft2(512x512) power spectrum -> radial profile (50 bins)
// -> per-batch KL divergence between softmaxed profiles of x and reference.
// 96 images (48 x + 48 ref), B=16, C=3, H=W=512. Output: 16 floats.
//
// R7: ZERO-ATOMIC BINNING. Cols was pinned at 72-76us across three structural
// variants; the invariant was 512 same-address-heavy LDS float atomics per
// column (neighboring lanes share a radial bin -> serialized on the per-CU
// LDS atomic path; not counted by SQ_LDS_BANK_CONFLICT). Replaced by: power
// -> LDS (natural k order) -> wave-wide prefix sum (b128 loads + shfl scan)
// -> each bin = two prefix differences (bin intervals are contiguous in k
// because radius is monotone in |sy|). Bin boundaries via sqrt estimate +
// fixup against the SAME binOf() used per-pixel before (exact consistency).

#define NIMG 96
#define NB 50
#define NCOL 257
#define PHYS(k) ((k) ^ (((k) >> 3) & 7))

typedef unsigned int uint32;

__device__ __forceinline__ float2 cadd(float2 a, float2 b){ return make_float2(a.x+b.x, a.y+b.y); }
__device__ __forceinline__ float2 csub(float2 a, float2 b){ return make_float2(a.x-b.x, a.y-b.y); }
__device__ __forceinline__ float2 cmul(float2 a, float2 b){
  return make_float2(fmaf(a.x, b.x, -(a.y*b.y)), fmaf(a.x, b.y, a.y*b.x));
}
__device__ __forceinline__ float2 mul_mi(float2 a){ return make_float2(a.y, -a.x); }  // * -i

// pack complex -> bf16x2 (re high, im low), RNE
__device__ __forceinline__ uint32 bfpack(float re, float im) {
  uint32 ur = __float_as_uint(re); ur += 0x7FFFu + ((ur >> 16) & 1u);
  uint32 ui = __float_as_uint(im); ui += 0x7FFFu + ((ui >> 16) & 1u);
  return (ur & 0xFFFF0000u) | (ui >> 16);
}
__device__ __forceinline__ float2 bfunpack(uint32 u) {
  return make_float2(__uint_as_float(u & 0xFFFF0000u), __uint_as_float(u << 16));
}

// 8 complex values in named registers.
struct C8 { float2 m0, m1, m2, m3, m4, m5, m6, m7; };

// 8-point DFT, natural order (by value).
__device__ __forceinline__ C8 fft8(C8 v) {
  const float C = 0.70710678118654752f;
  float2 t0=cadd(v.m0,v.m4), t1=csub(v.m0,v.m4);
  float2 t2=cadd(v.m2,v.m6), t3m=mul_mi(csub(v.m2,v.m6));
  float2 E0=cadd(t0,t2), E1=cadd(t1,t3m), E2=csub(t0,t2), E3=csub(t1,t3m);
  float2 s0=cadd(v.m1,v.m5), s1=csub(v.m1,v.m5);
  float2 s2=cadd(v.m3,v.m7), s3m=mul_mi(csub(v.m3,v.m7));
  float2 O0=cadd(s0,s2), O1=cadd(s1,s3m), O2=csub(s0,s2), O3=csub(s1,s3m);
  O1 = make_float2(C*(O1.x+O1.y), C*(O1.y-O1.x));      // * W8^1
  O2 = mul_mi(O2);                                      // * W8^2
  O3 = make_float2(C*(O3.y-O3.x), -C*(O3.x+O3.y));      // * W8^3
  C8 r;
  r.m0=cadd(E0,O0); r.m4=csub(E0,O0);
  r.m1=cadd(E1,O1); r.m5=csub(E1,O1);
  r.m2=cadd(E2,O2); r.m6=csub(E2,O2);
  r.m3=cadd(E3,O3); r.m7=csub(E3,O3);
  return r;
}

// twiddle recurrence applied to members 1..7 of XA and XB (shared t chain)
#define TWAPPLY(XA, XB, W) do { float2 t_ = (W);                        \
  XA.m1=cmul(XA.m1,t_); XB.m1=cmul(XB.m1,t_); t_=cmul(t_,(W));          \
  XA.m2=cmul(XA.m2,t_); XB.m2=cmul(XB.m2,t_); t_=cmul(t_,(W));          \
  XA.m3=cmul(XA.m3,t_); XB.m3=cmul(XB.m3,t_); t_=cmul(t_,(W));          \
  XA.m4=cmul(XA.m4,t_); XB.m4=cmul(XB.m4,t_); t_=cmul(t_,(W));          \
  XA.m5=cmul(XA.m5,t_); XB.m5=cmul(XB.m5,t_); t_=cmul(t_,(W));          \
  XA.m6=cmul(XA.m6,t_); XB.m6=cmul(XB.m6,t_); t_=cmul(t_,(W));          \
  XA.m7=cmul(XA.m7,t_); XB.m7=cmul(XB.m7,t_); } while(0)

// Dual wave-local 512-pt FFT (two independent FFTs, phase-interleaved).
#define DUAL_FFT512(XA, XB, ZA, ZB, W1, W2, HI, LO) do {                      \
  XA = fft8(XA); XB = fft8(XB);                                               \
  TWAPPLY(XA, XB, W1);                                                        \
  ZA[      8*((HI)^0)+(LO)] = XA.m0;  ZB[      8*((HI)^0)+(LO)] = XB.m0;      \
  ZA[ 64 + 8*((HI)^1)+(LO)] = XA.m1;  ZB[ 64 + 8*((HI)^1)+(LO)] = XB.m1;      \
  ZA[128 + 8*((HI)^2)+(LO)] = XA.m2;  ZB[128 + 8*((HI)^2)+(LO)] = XB.m2;      \
  ZA[192 + 8*((HI)^3)+(LO)] = XA.m3;  ZB[192 + 8*((HI)^3)+(LO)] = XB.m3;      \
  ZA[256 + 8*((HI)^4)+(LO)] = XA.m4;  ZB[256 + 8*((HI)^4)+(LO)] = XB.m4;      \
  ZA[320 + 8*((HI)^5)+(LO)] = XA.m5;  ZB[320 + 8*((HI)^5)+(LO)] = XB.m5;      \
  ZA[384 + 8*((HI)^6)+(LO)] = XA.m6;  ZB[384 + 8*((HI)^6)+(LO)] = XB.m6;      \
  ZA[448 + 8*((HI)^7)+(LO)] = XA.m7;  ZB[448 + 8*((HI)^7)+(LO)] = XB.m7;      \
  __builtin_amdgcn_wave_barrier();                                            \
  XA.m0 = ZA[64*(HI)+8*(0^(HI))+(LO)]; XB.m0 = ZB[64*(HI)+8*(0^(HI))+(LO)];   \
  XA.m1 = ZA[64*(HI)+8*(1^(HI))+(LO)]; XB.m1 = ZB[64*(HI)+8*(1^(HI))+(LO)];   \
  XA.m2 = ZA[64*(HI)+8*(2^(HI))+(LO)]; XB.m2 = ZB[64*(HI)+8*(2^(HI))+(LO)];   \
  XA.m3 = ZA[64*(HI)+8*(3^(HI))+(LO)]; XB.m3 = ZB[64*(HI)+8*(3^(HI))+(LO)];   \
  XA.m4 = ZA[64*(HI)+8*(4^(HI))+(LO)]; XB.m4 = ZB[64*(HI)+8*(4^(HI))+(LO)];   \
  XA.m5 = ZA[64*(HI)+8*(5^(HI))+(LO)]; XB.m5 = ZB[64*(HI)+8*(5^(HI))+(LO)];   \
  XA.m6 = ZA[64*(HI)+8*(6^(HI))+(LO)]; XB.m6 = ZB[64*(HI)+8*(6^(HI))+(LO)];   \
  XA.m7 = ZA[64*(HI)+8*(7^(HI))+(LO)]; XB.m7 = ZB[64*(HI)+8*(7^(HI))+(LO)];   \
  __builtin_amdgcn_wave_barrier();                                            \
  XA = fft8(XA); XB = fft8(XB);                                               \
  TWAPPLY(XA, XB, W2);                                                        \
  ZA[64*(HI)+8*(0^(HI))+((LO)^0)] = XA.m0; ZB[64*(HI)+8*(0^(HI))+((LO)^0)] = XB.m0; \
  ZA[64*(HI)+8*(1^(HI))+((LO)^1)] = XA.m1; ZB[64*(HI)+8*(1^(HI))+((LO)^1)] = XB.m1; \
  ZA[64*(HI)+8*(2^(HI))+((LO)^2)] = XA.m2; ZB[64*(HI)+8*(2^(HI))+((LO)^2)] = XB.m2; \
  ZA[64*(HI)+8*(3^(HI))+((LO)^3)] = XA.m3; ZB[64*(HI)+8*(3^(HI))+((LO)^3)] = XB.m3; \
  ZA[64*(HI)+8*(4^(HI))+((LO)^4)] = XA.m4; ZB[64*(HI)+8*(4^(HI))+((LO)^4)] = XB.m4; \
  ZA[64*(HI)+8*(5^(HI))+((LO)^5)] = XA.m5; ZB[64*(HI)+8*(5^(HI))+((LO)^5)] = XB.m5; \
  ZA[64*(HI)+8*(6^(HI))+((LO)^6)] = XA.m6; ZB[64*(HI)+8*(6^(HI))+((LO)^6)] = XB.m6; \
  ZA[64*(HI)+8*(7^(HI))+((LO)^7)] = XA.m7; ZB[64*(HI)+8*(7^(HI))+((LO)^7)] = XB.m7; \
  __builtin_amdgcn_wave_barrier();                                            \
  XA.m0 = ZA[64*(HI)+8*((LO)^(HI))+(0^(LO))]; XB.m0 = ZB[64*(HI)+8*((LO)^(HI))+(0^(LO))]; \
  XA.m1 = ZA[64*(HI)+8*((LO)^(HI))+(1^(LO))]; XB.m1 = ZB[64*(HI)+8*((LO)^(HI))+(1^(LO))]; \
  XA.m2 = ZA[64*(HI)+8*((LO)^(HI))+(2^(LO))]; XB.m2 = ZB[64*(HI)+8*((LO)^(HI))+(2^(LO))]; \
  XA.m3 = ZA[64*(HI)+8*((LO)^(HI))+(3^(LO))]; XB.m3 = ZB[64*(HI)+8*((LO)^(HI))+(3^(LO))]; \
  XA.m4 = ZA[64*(HI)+8*((LO)^(HI))+(4^(LO))]; XB.m4 = ZB[64*(HI)+8*((LO)^(HI))+(4^(LO))]; \
  XA.m5 = ZA[64*(HI)+8*((LO)^(HI))+(5^(LO))]; XB.m5 = ZB[64*(HI)+8*((LO)^(HI))+(5^(LO))]; \
  XA.m6 = ZA[64*(HI)+8*((LO)^(HI))+(6^(LO))]; XB.m6 = ZB[64*(HI)+8*((LO)^(HI))+(6^(LO))]; \
  XA.m7 = ZA[64*(HI)+8*((LO)^(HI))+(7^(LO))]; XB.m7 = ZB[64*(HI)+8*((LO)^(HI))+(7^(LO))]; \
  __builtin_amdgcn_wave_barrier();                                            \
  XA = fft8(XA); XB = fft8(XB);                                               \
} while(0)

#define TWIDDLE_W(W1, W2, lane)                                             \
  float2 W1, W2;                                                            \
  {                                                                         \
    float sv, cv;                                                           \
    __sincosf(-6.283185307179586f * (float)(lane) / 512.f, &sv, &cv);       \
    W1 = make_float2(cv, sv);                                               \
    __sincosf(-6.283185307179586f * (float)((lane) & 7) / 64.f, &sv, &cv);  \
    W2 = make_float2(cv, sv);                                               \
  }

// bin of a pixel at |sy|=s in column c — EXACT same formula as all prior
// (verified absmax 0.0) per-pixel rounds.
__device__ __forceinline__ int binOf(int s, int cc) {
  return (int)(sqrtf((float)(s * s + cc * cc)) * 0.1953125f);
}
// smallest s in [0,257] with binOf(s,cc) >= b (binOf monotone in s)
__device__ __forceinline__ int slo(int b, int cc) {
  if (b <= 0) return 0;
  float t = 26.2144f * (float)(b * b) - (float)(cc * cc);
  int s = (t <= 0.f) ? 0 : (int)ceilf(sqrtf(t));
  if (s > 257) s = 257;
  while (s > 0 && binOf(s - 1, cc) >= b) --s;
  while (s < 257 && binOf(s, cc) < b) ++s;
  return s;
}

// ---------------------------------------------------------------------------
// Row pass: unchanged from R6 (≈30us, near memory floor).
// ---------------------------------------------------------------------------
__global__ __launch_bounds__(256, 4) void fft_rows_T(
    const float* __restrict__ xin, const float* __restrict__ rin,
    uint32* __restrict__ outT, int img0)
{
  __shared__ float2 s_z[8][512];        // 32 KB
  __shared__ uint2  s_stage[64][8];     // 4 KB
  const int tid = threadIdx.x, w = tid >> 6, lane = tid & 63;
  const int hi = lane >> 3, lo = lane & 7;
  const int imgL = blockIdx.x >> 5, blkin = blockIdx.x & 31;
  const int img = img0 + imgL;
  const float* base = (img < 48) ? (xin + (size_t)img * 262144)
                                 : (rin + (size_t)(img - 48) * 262144);
  const int rpA = blkin * 8 + w;
  const int rpB = rpA + 4;
  const float* srcA = base + (size_t)rpA * 1024;
  const float* srcB = base + (size_t)rpB * 1024;

  TWIDDLE_W(w1, w2, lane)
  float2* zA = s_z[2*w];
  float2* zB = s_z[2*w + 1];
  uint32* outImg = outT + (size_t)imgL * ((size_t)NCOL * 512);

  C8 xA, xB;
  xA.m0 = make_float2(srcA[      lane], srcA[512 +       lane]);
  xA.m1 = make_float2(srcA[ 64 + lane], srcA[512 +  64 + lane]);
  xA.m2 = make_float2(srcA[128 + lane], srcA[512 + 128 + lane]);
  xA.m3 = make_float2(srcA[192 + lane], srcA[512 + 192 + lane]);
  xA.m4 = make_float2(srcA[256 + lane], srcA[512 + 256 + lane]);
  xA.m5 = make_float2(srcA[320 + lane], srcA[512 + 320 + lane]);
  xA.m6 = make_float2(srcA[384 + lane], srcA[512 + 384 + lane]);
  xA.m7 = make_float2(srcA[448 + lane], srcA[512 + 448 + lane]);
  xB.m0 = make_float2(srcB[      lane], srcB[512 +       lane]);
  xB.m1 = make_float2(srcB[ 64 + lane], srcB[512 +  64 + lane]);
  xB.m2 = make_float2(srcB[128 + lane], srcB[512 + 128 + lane]);
  xB.m3 = make_float2(srcB[192 + lane], srcB[512 + 192 + lane]);
  xB.m4 = make_float2(srcB[256 + lane], srcB[512 + 256 + lane]);
  xB.m5 = make_float2(srcB[320 + lane], srcB[512 + 320 + lane]);
  xB.m6 = make_float2(srcB[384 + lane], srcB[512 + 384 + lane]);
  xB.m7 = make_float2(srcB[448 + lane], srcB[512 + 448 + lane]);

  DUAL_FFT512(xA, xB, zA, zB, w1, w2, hi, lo);

  zA[PHYS(hi + 8*lo +   0)] = xA.m0;  zB[PHYS(hi + 8*lo +   0)] = xB.m0;
  zA[PHYS(hi + 8*lo +  64)] = xA.m1;  zB[PHYS(hi + 8*lo +  64)] = xB.m1;
  zA[PHYS(hi + 8*lo + 128)] = xA.m2;  zB[PHYS(hi + 8*lo + 128)] = xB.m2;
  zA[PHYS(hi + 8*lo + 192)] = xA.m3;  zB[PHYS(hi + 8*lo + 192)] = xB.m3;
  zA[PHYS(hi + 8*lo + 256)] = xA.m4;  zB[PHYS(hi + 8*lo + 256)] = xB.m4;
  zA[PHYS(hi + 8*lo + 320)] = xA.m5;  zB[PHYS(hi + 8*lo + 320)] = xB.m5;
  zA[PHYS(hi + 8*lo + 384)] = xA.m6;  zB[PHYS(hi + 8*lo + 384)] = xB.m6;
  zA[PHYS(hi + 8*lo + 448)] = xA.m7;  zB[PHYS(hi + 8*lo + 448)] = xB.m7;
  __builtin_amdgcn_wave_barrier();

  #pragma unroll
  for (int a = 0; a < 4; ++a) {
    const int k  = 64 * a + lane;
    const int pk = (512 - k) & 511;
    float2 zkA = zA[PHYS(k)], zpA = zA[PHYS(pk)];
    float2 zkB = zB[PHYS(k)], zpB = zB[PHYS(pk)];
    uint32 uA0 = bfpack(0.5f*(zkA.x + zpA.x), 0.5f*(zkA.y - zpA.y));
    uint32 uA1 = bfpack(0.5f*(zkA.y + zpA.y), 0.5f*(zpA.x - zkA.x));
    uint32 uB0 = bfpack(0.5f*(zkB.x + zpB.x), 0.5f*(zkB.y - zpB.y));
    uint32 uB1 = bfpack(0.5f*(zkB.y + zpB.y), 0.5f*(zpB.x - zkB.x));
    s_stage[lane][(w + lane) & 7]     = make_uint2(uA0, uA1);
    s_stage[lane][(w + 4 + lane) & 7] = make_uint2(uB0, uB1);
    __syncthreads();
    const int kk = tid >> 2, jj = (tid & 3) * 2;
    uint2 v0 = s_stage[kk][(jj + kk) & 7];
    uint2 v1 = s_stage[kk][(jj + 1 + kk) & 7];
    *reinterpret_cast<uint4*>(outImg + ((size_t)(64*a + kk) * 512
                                        + 16*blkin + 2*jj)) =
        make_uint4(v0.x, v0.y, v1.x, v1.y);
    __syncthreads();
  }
  if (lane == 0) {
    float2 znA = zA[256], znB = zB[256];
    *reinterpret_cast<uint2*>(outImg + ((size_t)256 * 512 + 2 * rpA)) =
        make_uint2(bfpack(znA.x, 0.f), bfpack(znA.y, 0.f));
    *reinterpret_cast<uint2*>(outImg + ((size_t)256 * 512 + 2 * rpB)) =
        make_uint2(bfpack(znB.x, 0.f), bfpack(znB.y, 0.f));
  }
}

// ---------------------------------------------------------------------------
// Col pass: TWO column FFTs per wave + ATOMIC-FREE radial binning via
// wave-wide prefix sum. Block = 4 waves = 8 columns; 33 blocks/image.
// ---------------------------------------------------------------------------
__global__ __launch_bounds__(256, 4) void fft_cols_bin(
    const uint32* __restrict__ inT, float* __restrict__ profSum, int img0)
{
  __shared__ float2 s_z[8][512];        // 32 KB
  __shared__ float s_bins[4][64];       // 1 KB
  const int tid = threadIdx.x, w = tid >> 6, lane = tid & 63;
  const int hi = lane >> 3, lo = lane & 7;
  const int imgL = blockIdx.x / 33, blkin = blockIdx.x - imgL * 33;
  const int imgG = img0 + imgL;
  const int cA = blkin * 8 + w;
  const int cB = cA + 4;
  const int csA = (cA <= 256) ? cA : 256;
  const int csB = (cB <= 256) ? cB : 256;
  const float wfA = (cA > 256) ? 0.f : ((cA == 0 || cA == 256) ? 1.f : 2.f);
  const float wfB = (cB > 256) ? 0.f : ((cB == 0 || cB == 256) ? 1.f : 2.f);

  TWIDDLE_W(w1, w2, lane)
  float2* zA = s_z[2*w];
  float2* zB = s_z[2*w + 1];
  const uint32* srcA = inT + ((size_t)(imgL * NCOL + csA)) * 512;
  const uint32* srcB = inT + ((size_t)(imgL * NCOL + csB)) * 512;
  C8 xA, xB;
  xA.m0 = bfunpack(srcA[      lane]);  xB.m0 = bfunpack(srcB[      lane]);
  xA.m1 = bfunpack(srcA[ 64 + lane]);  xB.m1 = bfunpack(srcB[ 64 + lane]);
  xA.m2 = bfunpack(srcA[128 + lane]);  xB.m2 = bfunpack(srcB[128 + lane]);
  xA.m3 = bfunpack(srcA[192 + lane]);  xB.m3 = bfunpack(srcB[192 + lane]);
  xA.m4 = bfunpack(srcA[256 + lane]);  xB.m4 = bfunpack(srcB[256 + lane]);
  xA.m5 = bfunpack(srcA[320 + lane]);  xB.m5 = bfunpack(srcB[320 + lane]);
  xA.m6 = bfunpack(srcA[384 + lane]);  xB.m6 = bfunpack(srcB[384 + lane]);
  xA.m7 = bfunpack(srcA[448 + lane]);  xB.m7 = bfunpack(srcB[448 + lane]);

  DUAL_FFT512(xA, xB, zA, zB, w1, w2, hi, lo);

  // ---- power -> LDS in natural k order (kout = hi+8lo+64q; conflict-free)
  float* zfA = (float*)zA;
  float* zfB = (float*)zB;
  const int low6 = hi + 8 * lo;
  zfA[low6      ] = xA.m0.x*xA.m0.x + xA.m0.y*xA.m0.y;
  zfA[low6 +  64] = xA.m1.x*xA.m1.x + xA.m1.y*xA.m1.y;
  zfA[low6 + 128] = xA.m2.x*xA.m2.x + xA.m2.y*xA.m2.y;
  zfA[low6 + 192] = xA.m3.x*xA.m3.x + xA.m3.y*xA.m3.y;
  zfA[low6 + 256] = xA.m4.x*xA.m4.x + xA.m4.y*xA.m4.y;
  zfA[low6 + 320] = xA.m5.x*xA.m5.x + xA.m5.y*xA.m5.y;
  zfA[low6 + 384] = xA.m6.x*xA.m6.x + xA.m6.y*xA.m6.y;
  zfA[low6 + 448] = xA.m7.x*xA.m7.x + xA.m7.y*xA.m7.y;
  zfB[low6      ] = xB.m0.x*xB.m0.x + xB.m0.y*xB.m0.y;
  zfB[low6 +  64] = xB.m1.x*xB.m1.x + xB.m1.y*xB.m1.y;
  zfB[low6 + 128] = xB.m2.x*xB.m2.x + xB.m2.y*xB.m2.y;
  zfB[low6 + 192] = xB.m3.x*xB.m3.x + xB.m3.y*xB.m3.y;
  zfB[low6 + 256] = xB.m4.x*xB.m4.x + xB.m4.y*xB.m4.y;
  zfB[low6 + 320] = xB.m5.x*xB.m5.x + xB.m5.y*xB.m5.y;
  zfB[low6 + 384] = xB.m6.x*xB.m6.x + xB.m6.y*xB.m6.y;
  zfB[low6 + 448] = xB.m7.x*xB.m7.x + xB.m7.y*xB.m7.y;
  __builtin_amdgcn_wave_barrier();

  // ---- load contiguous 8 per lane (b128 x2 each, 2 lanes/bank = free)
  float4 a0 = *reinterpret_cast<float4*>(&zfA[8 * lane]);
  float4 a1 = *reinterpret_cast<float4*>(&zfA[8 * lane + 4]);
  float4 b0 = *reinterpret_cast<float4*>(&zfB[8 * lane]);
  float4 b1 = *reinterpret_cast<float4*>(&zfB[8 * lane + 4]);

  // ---- local inclusive prefix over 8
  a0.y += a0.x; a0.z += a0.y; a0.w += a0.z;
  a1.x += a0.w; a1.y += a1.x; a1.z += a1.y; a1.w += a1.z;
  b0.y += b0.x; b0.z += b0.y; b0.w += b0.z;
  b1.x += b0.w; b1.y += b1.x; b1.z += b1.y; b1.w += b1.z;
  float totA = a1.w, totB = b1.w;

  // ---- wave inclusive scan of lane totals (both columns share the shfls)
  float sA = totA, sB = totB;
  #pragma unroll
  for (int d = 1; d < 64; d <<= 1) {
    float tA = __shfl_up(sA, d);
    float tB = __shfl_up(sB, d);
    if (lane >= d) { sA += tA; sB += tB; }
  }
  float offA = sA - totA, offB = sB - totB;
  a0.x += offA; a0.y += offA; a0.z += offA; a0.w += offA;
  a1.x += offA; a1.y += offA; a1.z += offA; a1.w += offA;
  b0.x += offB; b0.y += offB; b0.z += offB; b0.w += offB;
  b1.x += offB; b1.y += offB; b1.z += offB; b1.w += offB;

  // ---- write prefix back (same conflict-free b128 pattern)
  *reinterpret_cast<float4*>(&zfA[8 * lane])     = a0;
  *reinterpret_cast<float4*>(&zfA[8 * lane + 4]) = a1;
  *reinterpret_cast<float4*>(&zfB[8 * lane])     = b0;
  *reinterpret_cast<float4*>(&zfB[8 * lane + 4]) = b1;
  __builtin_amdgcn_wave_barrier();

  // ---- bin extraction: bin b = two prefix differences
  float acc = 0.f;
  if (lane < NB) {
    // column A
    {
      int s0 = slo(lane, csA), s1 = slo(lane + 1, csA);
      int hp = (s1 < 257 ? s1 : 257) - 1;
      float pos = ((hp >= 0) ? zfA[hp] : 0.f) - ((s0 > 0) ? zfA[s0 - 1] : 0.f);
      int sa = (s0 > 1) ? s0 : 1;
      int sb = (s1 - 1 < 255) ? (s1 - 1) : 255;
      float neg = (sb >= sa) ? (zfA[512 - sa] - zfA[511 - sb]) : 0.f;
      acc += wfA * (pos + neg);
    }
    // column B
    {
      int s0 = slo(lane, csB), s1 = slo(lane + 1, csB);
      int hp = (s1 < 257 ? s1 : 257) - 1;
      float pos = ((hp >= 0) ? zfB[hp] : 0.f) - ((s0 > 0) ? zfB[s0 - 1] : 0.f);
      int sa = (s0 > 1) ? s0 : 1;
      int sb = (s1 - 1 < 255) ? (s1 - 1) : 255;
      float neg = (sb >= sa) ? (zfB[512 - sa] - zfB[511 - sb]) : 0.f;
      acc += wfB * (pos + neg);
    }
  }
  s_bins[w][lane] = acc;          // plain write, no atomics
  __syncthreads();
  if (tid < NB) {
    float s = s_bins[0][tid] + s_bins[1][tid] + s_bins[2][tid] + s_bins[3][tid];
    atomicAdd(&profSum[(size_t)imgG * NB + tid], s);
  }
}

// ---------------------------------------------------------------------------
// Radial bin counts (geometry only). 128 blocks x 2048 pixels.
// ---------------------------------------------------------------------------
__global__ __launch_bounds__(256) void compute_counts(float* __restrict__ cnt)
{
  const int t = threadIdx.x;
  __shared__ float lb[NB];
  if (t < NB) lb[t] = 0.f;
  __syncthreads();
  const int base = blockIdx.x * 2048;
  #pragma unroll
  for (int k = 0; k < 8; ++k) {
    const int idx = base + k * 256 + t;
    const int y  = idx >> 9;
    const int xx = idx & 511;
    const int sy = (y < 256) ? y : y - 512;
    const int sx = (xx < 256) ? xx : xx - 512;
    float r = sqrtf((float)(sy * sy + sx * sx));
    int bb = (int)(r * 0.1953125f);
    if (bb < NB) atomicAdd(&lb[bb], 1.f);
  }
  __syncthreads();
  if (t < NB) atomicAdd(&cnt[t], lb[t]);
}

// ---------------------------------------------------------------------------
// Finalize: profile means -> log_softmax -> KL. One block per batch.
// ---------------------------------------------------------------------------
__global__ __launch_bounds__(256) void finalize_kl(
    const float* __restrict__ profSum, const float* __restrict__ cntg,
    float* __restrict__ out)
{
  const int b = blockIdx.x;
  const int t = threadIdx.x;
  __shared__ float red[256];

  float lxv = -3.0e38f, lrv = -3.0e38f;
  if (t < 150) {
    const int cc  = t / NB;
    const int bin = t - cc * NB;
    const float c = cntg[bin];
    lxv = profSum[(size_t)(b * 3 + cc) * NB + bin] / c;
    lrv = profSum[(size_t)(48 + b * 3 + cc) * NB + bin] / c;
  }
  auto rmax = [&](float v) {
    red[t] = v; __syncthreads();
    for (int s2 = 128; s2 >= 1; s2 >>= 1) {
      if (t < s2) red[t] = fmaxf(red[t], red[t + s2]);
      __syncthreads();
    }
    float rr = red[0]; __syncthreads();
    return rr;
  };
  auto rsum = [&](float v) {
    red[t] = v; __syncthreads();
    for (int s2 = 128; s2 >= 1; s2 >>= 1) {
      if (t < s2) red[t] = red[t] + red[t + s2];
      __syncthreads();
    }
    float rr = red[0]; __syncthreads();
    return rr;
  };
  const float mx  = rmax(lxv);
  const float mr  = rmax(lrv);
  const float sx  = rsum((t < 150) ? expf(lxv - mx) : 0.f);
  const float sr  = rsum((t < 150) ? expf(lrv - mr) : 0.f);
  const float lsx = logf(sx);
  const float lsr = logf(sr);
  float term = 0.f;
  if (t < 150) {
    const float logp = lxv - mx - lsx;
    const float logq = lrv - mr - lsr;
    const float q    = expf(logq);
    term = q * (logq - logp);
  }
  const float div = rsum(term);
  if (t == 0) out[b] = div;
}

// ---------------------------------------------------------------------------
extern "C" void kernel_launch(void* const* d_in, const int* in_sizes, int n_in,
                              void* d_out, int out_size, void* d_ws, size_t ws_size,
                              hipStream_t stream)
{
  const float* x = (const float*)d_in[0];
  const float* r = (const float*)d_in[1];
  float* out     = (float*)d_out;

  float* profSum = (float*)d_ws;
  float* cnt     = (float*)((char*)d_ws + 19200);
  const size_t IM_OFS = 19456;
  uint32* interT = (uint32*)((char*)d_ws + IM_OFS);

  const size_t perImg = (size_t)NCOL * 512 * sizeof(uint32);  // ~514 KiB
  size_t avail = (ws_size > IM_OFS) ? (ws_size - IM_OFS) : 0;
  int ic = (int)(avail / perImg);
  if (ic > NIMG) ic = NIMG;
  if (ic < 1) ic = 1;

  hipMemsetAsync(d_ws, 0, IM_OFS, stream);
  hipLaunchKernelGGL(compute_counts, dim3(128), dim3(256), 0, stream, cnt);

  for (int img0 = 0; img0 < NIMG; img0 += ic) {
    const int n = (NIMG - img0 < ic) ? (NIMG - img0) : ic;
    hipLaunchKernelGGL(fft_rows_T, dim3(n * 32), dim3(256), 0, stream,
                       x, r, interT, img0);
    hipLaunchKernelGGL(fft_cols_bin, dim3(n * 33), dim3(256), 0, stream,
                       interT, profSum, img0);
  }
  hipLaunchKernelGGL(finalize_kl, dim3(16), dim3(256), 0, stream,
                     profSum, cnt, out);
}